// Round 1
// 197.625 us; speedup vs baseline: 1.0472x; 1.0472x over previous
//
#include <hip/hip_runtime.h>
#include <hip/hip_bf16.h>
#include <math.h>

#define B_ 4
#define T_ 2048
#define C_ 768
#define H_ 12
#define D_ 64
#define R_ 64
#define BT_ (B_*T_)   /* 8192 */
#define HD_ (H_*D_)   /* 768  */

typedef __attribute__((ext_vector_type(8))) short bf16x8;
typedef __attribute__((ext_vector_type(4))) float f32x4;
typedef __attribute__((ext_vector_type(16))) float f32x16;

__device__ inline short f2bf(float f) {
  union { float f; unsigned u; } x; x.f = f;
  unsigned r = x.u + 0x7fffu + ((x.u >> 16) & 1u);
  return (short)(r >> 16);
}
__device__ inline unsigned pk_bf16(float a, float b) {
#if __has_builtin(__builtin_amdgcn_cvt_pk_bf16_f32)
  auto t = __builtin_amdgcn_cvt_pk_bf16_f32(a, b);
  unsigned u; __builtin_memcpy(&u, &t, sizeof(unsigned)); return u;
#else
  union { float f; unsigned u; } x, y; x.f = a; y.f = b;
  unsigned ra = (x.u + 0x7fffu + ((x.u >> 16) & 1u)) >> 16;
  unsigned rb = (y.u + 0x7fffu + ((y.u >> 16) & 1u)) & 0xffff0000u;
  return ra | rb;
#endif
}
__device__ inline float fexp2(float x) {
#if __has_builtin(__builtin_amdgcn_exp2f)
  return __builtin_amdgcn_exp2f(x);
#else
  return exp2f(x);
#endif
}
// cross-half (lane i <-> lane i+32) word swap:
// a <- {a.lanes0-31, b.lanes0-31}; b <- {a.lanes32-63, b.lanes32-63}
__device__ inline void pswap(unsigned &a, unsigned &b) {
#if __has_builtin(__builtin_amdgcn_permlane32_swap)
  auto r = __builtin_amdgcn_permlane32_swap((int)a, (int)b, false, false);
  unsigned u[2]; __builtin_memcpy(u, &r, 8);
  a = u[0]; b = u[1];
#else
  unsigned ax = __shfl_xor(a, 32), bx = __shfl_xor(b, 32);
  bool hi = (threadIdx.x & 32) != 0;
  unsigned na = hi ? bx : a;
  unsigned nb = hi ? b : ax;
  a = na; b = nb;
#endif
}
typedef __attribute__((address_space(3))) unsigned lds_u32;
typedef __attribute__((address_space(1))) const unsigned glb_u32;
__device__ inline void gload_lds16(const void* g, void* l) {
  __builtin_amdgcn_global_load_lds((glb_u32*)g, (lds_u32*)l, 16, 0, 0);
}

// ---------------- fused convert(x) + weight transposes + RoPE table ----------------
__device__ inline void ttile(const float* __restrict__ src, short* __restrict__ dst,
                             int K, int N, int k0, int n0, int tid, float (*tl)[33]) {
  int tx = tid & 31, ty = tid >> 5;
  #pragma unroll
  for (int r = 0; r < 4; ++r)
    tl[ty + 8 * r][tx] = src[(size_t)(k0 + ty + 8 * r) * N + n0 + tx];
  __syncthreads();
  #pragma unroll
  for (int r = 0; r < 4; ++r)
    dst[(size_t)(n0 + ty + 8 * r) * K + k0 + tx] = f2bf(tl[tx][ty + 8 * r]);
}

#define NCONV (BT_*C_/4/256)   /* 6144 blocks for x convert */

__global__ __launch_bounds__(256) void prep_conv(
    const float* __restrict__ x, short* __restrict__ x_bf,
    const float* __restrict__ Wq, const float* __restrict__ Wd,
    const float* __restrict__ Wup, const float* __restrict__ Wo,
    short* __restrict__ W1T, short* __restrict__ WupT, short* __restrict__ WoT,
    float* __restrict__ cs, float* __restrict__ sn) {
  __shared__ float tl[32][33];
  int tid = threadIdx.x;
  if (blockIdx.x < NCONV) {          // convert x -> bf16
    int i = blockIdx.x * 256 + tid;
    float4 v = ((const float4*)x)[i];
    short4 o;
    o.x = f2bf(v.x); o.y = f2bf(v.y); o.z = f2bf(v.z); o.w = f2bf(v.w);
    ((short4*)x_bf)[i] = o;
    return;
  }
  int blk = blockIdx.x - NCONV;
  if (blk < 576) {                    // Wq: K=768,N=768 -> W1T rows 0..767
    int tk = blk % 24, tn = blk / 24;
    ttile(Wq, W1T, 768, 768, tk * 32, tn * 32, tid, tl);
  } else if (blk < 624) {             // Wd: K=768,N=64 -> W1T rows 768..831
    int l = blk - 576; int tk = l % 24, tn = l / 24;
    ttile(Wd, W1T + (size_t)768 * 768, 768, 64, tk * 32, tn * 32, tid, tl);
  } else if (blk < 720) {             // Wup: K=64,N=1536
    int l = blk - 624; int tk = l % 2, tn = l / 2;
    ttile(Wup, WupT, 64, 1536, tk * 32, tn * 32, tid, tl);
  } else if (blk < 1296) {            // Wo: K=768,N=768
    int l = blk - 720; int tk = l % 24, tn = l / 24;
    ttile(Wo, WoT, 768, 768, tk * 32, tn * 32, tid, tl);
  } else {                            // rope table
    int base = (blk - 1296) * 1024;
    #pragma unroll
    for (int i = 0; i < 4; ++i) {
      int idx = base + tid + i * 256;
      int j = idx & 31, t = idx >> 5;
      float invf = exp2f(-(float)j * (13.287712379549449f / 32.f)); // 10000^(-j/32)
      float a = (float)t * invf;
      cs[idx] = cosf(a);
      sn[idx] = sinf(a);
    }
  }
}

// ---------------- 128x64-tile GEMM ----------------
// C[M,N] = A[M,K](bf16) * Bt[N,K](bf16)^T, BK=64. Wave w owns rows [w*32,+32).
// MODE 0: y<12 -> q*SC2+rope -> ob0 [BH][T][64]; y==12 -> LN(ckv) -> ob1 [M][64]
// MODE 1: y<12 -> k+rope -> ob0; y>=12 -> v transposed -> ob1 [BH*64][T]
// MODE 2: out0[row*N+col] = acc + bias[col]
#define SC2_ 0.18033688f   /* 0.125 * log2(e) */

template<int MODE>
__global__ __launch_bounds__(256) void gemm64(
    const short* __restrict__ A, const short* __restrict__ Bt,
    int M, int N, int K,
    float* __restrict__ out0, const float* __restrict__ bias,
    const float* __restrict__ bias2,
    short* __restrict__ ob0, short* __restrict__ ob1,
    const float* __restrict__ cs, const float* __restrict__ sn)
{
  __shared__ short SM[128 * 64 + 64 * 64];  // As (16KB) | Bs (8KB)
  short* As = SM;
  short* Bs = SM + 128 * 64;
  const int m0 = blockIdx.x * 128;
  const int n0 = blockIdx.y * 64;
  const int tid = threadIdx.x, lane = tid & 63, w = tid >> 6;
  const int fr = lane & 15, fk = (lane >> 4) * 8;
  const int rstage = lane >> 3;
  const int cstage = (lane & 7) * 8;

  f32x4 acc[2][4] = {};

  for (int k0 = 0; k0 < K; k0 += 64) {
    __syncthreads();
    #pragma unroll
    for (int i = 0; i < 4; ++i) {          // A: 16 chunks
      int c = w * 4 + i;
      int r = c * 8 + rstage;
      gload_lds16(&A[(size_t)(m0 + r) * K + k0 + cstage], &As[c * 512]);
    }
    #pragma unroll
    for (int i = 0; i < 2; ++i) {          // B: 8 chunks
      int c = w * 2 + i;
      int r = c * 8 + rstage;
      gload_lds16(&Bt[(size_t)(n0 + r) * K + k0 + cstage], &Bs[c * 512]);
    }
    __syncthreads();
    #pragma unroll
    for (int kk = 0; kk < 64; kk += 32) {
      bf16x8 a[2], b[4];
      a[0] = *(const bf16x8*)&As[(w * 32 +      fr) * 64 + kk + fk];
      a[1] = *(const bf16x8*)&As[(w * 32 + 16 + fr) * 64 + kk + fk];
      #pragma unroll
      for (int ni = 0; ni < 4; ++ni)
        b[ni] = *(const bf16x8*)&Bs[(ni * 16 + fr) * 64 + kk + fk];
      #pragma unroll
      for (int mi = 0; mi < 2; ++mi)
        #pragma unroll
        for (int ni = 0; ni < 4; ++ni)
          acc[mi][ni] = __builtin_amdgcn_mfma_f32_16x16x32_bf16(a[mi], b[ni], acc[mi][ni], 0, 0, 0);
    }
  }

  const int er = (lane >> 4) * 4, ec = lane & 15;

  if constexpr (MODE == 2) {
    #pragma unroll
    for (int mi = 0; mi < 2; ++mi)
      #pragma unroll
      for (int r = 0; r < 4; ++r) {
        int row = m0 + w * 32 + mi * 16 + er + r;
        #pragma unroll
        for (int ni = 0; ni < 4; ++ni) {
          int col = n0 + ni * 16 + ec;
          out0[(size_t)row * N + col] = acc[mi][ni][r] + bias[col];
        }
      }
    return;
  }

  if (n0 < 768) {  // q (MODE0) or k (MODE1), fused RoPE (+ SC2 scale for q)
    int h = n0 >> 6;
    #pragma unroll
    for (int mi = 0; mi < 2; ++mi)
      #pragma unroll
      for (int r = 0; r < 4; ++r) {
        int row = m0 + w * 32 + mi * 16 + er + r;
        int t = row & (T_ - 1), bb = row >> 11;
        short* dst = ob0 + (((size_t)(bb * H_ + h)) * T_ + t) * 64;
        #pragma unroll
        for (int ni = 0; ni < 2; ++ni) {
          int d = ni * 16 + ec;
          float c = cs[t * 32 + d], s = sn[t * 32 + d];
          if constexpr (MODE == 0) { c *= SC2_; s *= SC2_; }
          float x0 = acc[mi][ni][r], x1 = acc[mi][ni + 2][r];
          dst[d]      = f2bf(x0 * c - x1 * s);
          dst[d + 32] = f2bf(x1 * c + x0 * s);
        }
      }
  } else if constexpr (MODE == 0) {
    // ckv tile (n0 == 768): fused LayerNorm. bias=ln_g, bias2=ln_b
    #pragma unroll
    for (int mi = 0; mi < 2; ++mi)
      #pragma unroll
      for (int r = 0; r < 4; ++r) {
        float s = 0.f, s2 = 0.f;
        #pragma unroll
        for (int ni = 0; ni < 4; ++ni) { float v = acc[mi][ni][r]; s += v; s2 += v*v; }
        #pragma unroll
        for (int off = 1; off < 16; off <<= 1) {
          s  += __shfl_xor(s, off);
          s2 += __shfl_xor(s2, off);
        }
        float mu = s * (1.f/64.f);
        float var = s2 * (1.f/64.f) - mu * mu;
        float rstd = rsqrtf(var + 1e-5f);
        int row = m0 + w * 32 + mi * 16 + er + r;
        #pragma unroll
        for (int ni = 0; ni < 4; ++ni) {
          int d = ni * 16 + ec;
          ob1[(size_t)row * 64 + d] = f2bf((acc[mi][ni][r] - mu) * rstd * bias[d] + bias2[d]);
        }
      }
  } else {
    // MODE 1 v tile: acc -> wave-private LDS (stride 40) -> coalesced vt stores
    __syncthreads();   // all waves done reading As/Bs
    short* Wl = SM + w * 2560;     // 64 d-rows x 40 shorts
    int h = (n0 - 768) >> 6;
    #pragma unroll
    for (int mi = 0; mi < 2; ++mi) {
      int tl0 = mi * 16 + er;
      #pragma unroll
      for (int ni = 0; ni < 4; ++ni) {
        int d = ni * 16 + ec;
        uint2 uu;
        uu.x = pk_bf16(acc[mi][ni][0], acc[mi][ni][1]);
        uu.y = pk_bf16(acc[mi][ni][2], acc[mi][ni][3]);
        *(uint2*)&Wl[d * 40 + tl0] = uu;
      }
    }
    int bb = m0 >> 11;
    int tg0 = (m0 & (T_ - 1)) + w * 32;
    int dl = lane >> 2, tl = (lane & 3) * 8;
    #pragma unroll
    for (int j = 0; j < 4; ++j) {
      int d = j * 16 + dl;
      uint4 vv = *(const uint4*)&Wl[d * 40 + tl];
      *(uint4*)&ob1[((size_t)(bb * H_ + h) * 64 + d) * T_ + tg0 + tl] = vv;
    }
  }
}

// ---------------- MFMA flash attention v8 ----------------
// v7 + : (1) double-buffered K/V staging (T3-minimum 2-phase): stage tile t+1
// while computing tile t, ONE barrier per tile -> global->LDS latency hidden
// under compute (v7 drained vmcnt(0) on the critical path every tile; counters:
// MfmaUtil 14%, HBM 5%, ~50% idle).
// (2) P in-register via cvt_pk + permlane32_swap (T12): C-layout->B-frag needs
// only lane<->lane+32 word exchange. {w0,w2}=swap(pkLo(2ks),pkLo(2ks+1)),
// {w1,w3}=swap(pkHi(2ks),pkHi(2ks+1)). Kills the Ps round-trip (8 ds_write +
// 4 ds_read_b128/tile, 1.74M bank-conflict cycles) and frees 18KB LDS; epilogue
// O-transpose reuses the dead K/V buffers. LDS 34.8KB -> 32KB.
// (3) per-lane l partials, one shfl_xor(.,32) at epilogue.
// (4) s_setprio(1) around MFMA clusters (T5, measured + on attn).
// 32x32 C/D layout (m74/m101): col=lane&31, row=(reg&3)+8*(reg>>2)+4*(lane>>5).
__global__ __launch_bounds__(256) void attn_mfma(
    const short* __restrict__ qgl, const short* __restrict__ kg,
    const short* __restrict__ vtg, short* __restrict__ o)
{
  // [buf][0=K,1=V][8 chunks * 512 shorts]; chunk c=kh*4+ks:
  //   K: K[kt+kh*32+(L&31)][ks*16+(L>>5)*8]   V: V^T[dt*32+(L&31)][kt+ks*16+(L>>5)*8]
  __shared__ short SMa[2][2][8 * 512];   // 32 KB total

  const int bh = blockIdx.x;           // 0..47
  const int y  = blockIdx.y;           // 0..15 (y=0 dispatches first = longest)
  const int qt1 = 31 - y, qt2 = y;
  const int tid = threadIdx.x, lane = tid & 63, w = tid >> 6;
  const int q32 = lane & 31, half = lane >> 5;
  const short* kb  = kg  + (size_t)bh * T_ * 64;
  const short* vtb = vtg + (size_t)bh * 64 * T_;
  const int b = bh / H_, h = bh - b * H_;

  const int qt_w = (w < 2) ? qt1 : qt2;
  const int q0 = qt_w * 64 + (w & 1) * 32;
  const int last_w = qt_w * 64;
  const int qidx = q0 + q32;

  // Q B-frags: bq[ks] = Q[q0+q32][ks*16 + half*8 .. +8]
  const short* qrow = qgl + ((size_t)bh * T_ + qidx) * 64;
  bf16x8 bq[4];
  #pragma unroll
  for (int ks = 0; ks < 4; ++ks)
    bq[ks] = *(const bf16x8*)&qrow[ks * 16 + half * 8];

  f32x16 oacc[2] = {};
  float lrun = 0.f;
  const int kend = qt1 * 64;

  auto stage = [&](int buf, int kt) {
    #pragma unroll
    for (int i = 0; i < 2; ++i) {      // wave w stages chunks {2w, 2w+1}
      int c = w * 2 + i;
      int kh = c >> 2, ks = c & 3;
      gload_lds16(kb + (size_t)(kt + kh * 32 + q32) * 64 + ks * 16 + half * 8,
                  &SMa[buf][0][c * 512]);
      gload_lds16(vtb + (size_t)(kh * 32 + q32) * T_ + kt + ks * 16 + half * 8,
                  &SMa[buf][1][c * 512]);
    }
  };

  stage(0, 0);
  __syncthreads();                     // buf0 ready

  int cur = 0;
  for (int kt = 0; kt <= kend; kt += 64) {
    if (kt + 64 <= kend) stage(cur ^ 1, kt + 64);   // async prefetch next tile

    if (kt <= last_w) {
      const short* Kc = &SMa[cur][0][0];
      const short* Vc = &SMa[cur][1][0];
      const bool diag = (kt == last_w);
      const int dkh = diag ? (w & 1) : 2; // which kh is diagonal-masked
      const bool skip1 = diag && ((w & 1) == 0);

      bf16x8 bp[4];
      #pragma unroll
      for (int kh = 0; kh < 2; ++kh) {
        if (kh == 1 && skip1) break;    // fully-masked upper half of diag tile
        f32x16 sacc = {};
        __builtin_amdgcn_s_setprio(1);
        #pragma unroll
        for (int ks = 0; ks < 4; ++ks) {
          bf16x8 a = *(const bf16x8*)&Kc[(kh * 4 + ks) * 512 + lane * 8];
          sacc = __builtin_amdgcn_mfma_f32_32x32x16_bf16(a, bq[ks], sacc, 0, 0, 0);
        }
        __builtin_amdgcn_s_setprio(0);
        float pv[16];
        if (kh != dkh) {
          #pragma unroll
          for (int r = 0; r < 16; ++r) { float p = fexp2(sacc[r]); pv[r] = p; lrun += p; }
        } else {
          #pragma unroll
          for (int r = 0; r < 16; ++r) {
            int key = kt + kh * 32 + (r & 3) + 8 * (r >> 2) + 4 * half;
            float p = (key <= qidx) ? fexp2(sacc[r]) : 0.f;
            pv[r] = p; lrun += p;
          }
        }
        // C-layout -> B-frag, in-register (no LDS):
        unsigned l0 = pk_bf16(pv[0],  pv[1]),  h0 = pk_bf16(pv[2],  pv[3]);
        unsigned l1 = pk_bf16(pv[4],  pv[5]),  h1 = pk_bf16(pv[6],  pv[7]);
        unsigned l2 = pk_bf16(pv[8],  pv[9]),  h2 = pk_bf16(pv[10], pv[11]);
        unsigned l3 = pk_bf16(pv[12], pv[13]), h3 = pk_bf16(pv[14], pv[15]);
        pswap(l0, l1); pswap(h0, h1);
        pswap(l2, l3); pswap(h2, h3);
        union { unsigned u[4]; bf16x8 v; } f0, f1;
        f0.u[0] = l0; f0.u[1] = h0; f0.u[2] = l1; f0.u[3] = h1;
        f1.u[0] = l2; f1.u[1] = h2; f1.u[2] = l3; f1.u[3] = h3;
        bp[2 * kh + 0] = f0.v;
        bp[2 * kh + 1] = f1.v;
      }

      __builtin_amdgcn_s_setprio(1);
      #pragma unroll
      for (int ks = 0; ks < 2; ++ks)
        #pragma unroll
        for (int dt = 0; dt < 2; ++dt) {
          bf16x8 av = *(const bf16x8*)&Vc[(dt * 4 + ks) * 512 + lane * 8];
          oacc[dt] = __builtin_amdgcn_mfma_f32_32x32x16_bf16(av, bp[ks], oacc[dt], 0, 0, 0);
        }
      if (!skip1) {
        #pragma unroll
        for (int ks = 2; ks < 4; ++ks)
          #pragma unroll
          for (int dt = 0; dt < 2; ++dt) {
            bf16x8 av = *(const bf16x8*)&Vc[(dt * 4 + ks) * 512 + lane * 8];
            oacc[dt] = __builtin_amdgcn_mfma_f32_32x32x16_bf16(av, bp[ks], oacc[dt], 0, 0, 0);
          }
      }
      __builtin_amdgcn_s_setprio(0);
    }

    __syncthreads();    // compiler drains vmcnt(0): prefetch had a full compute phase to land
    cur ^= 1;
  }

  // epilogue: scale, O^T (C-layout) -> wave-private LDS (reusing dead K/V bufs)
  // -> coalesced rows. Last loop barrier guarantees all K/V reads are done.
  float ltot = lrun + __shfl_xor(lrun, 32);
  float inv = 1.f / ltot;
  short* Pw = &SMa[0][0][0] + w * 2304;   // 32 rows x 72 shorts per wave
  #pragma unroll
  for (int dt = 0; dt < 2; ++dt)
    #pragma unroll
    for (int g2 = 0; g2 < 4; ++g2) {
      uint2 uu;
      uu.x = pk_bf16(oacc[dt][4 * g2 + 0] * inv, oacc[dt][4 * g2 + 1] * inv);
      uu.y = pk_bf16(oacc[dt][4 * g2 + 2] * inv, oacc[dt][4 * g2 + 3] * inv);
      *(uint2*)&Pw[q32 * 72 + dt * 32 + 8 * g2 + 4 * half] = uu;
    }
  int row = lane >> 1, seg = lane & 1;
  int t = q0 + row;
  short* orow = o + ((size_t)(b * T_ + t)) * HD_ + h * 64 + seg * 32;
  #pragma unroll
  for (int i = 0; i < 4; ++i) {
    uint4 vv = *(const uint4*)&Pw[row * 72 + seg * 32 + i * 8];
    *(uint4*)&orow[i * 8] = vv;
  }
}

// ---------------- launcher ----------------
extern "C" void kernel_launch(void* const* d_in, const int* in_sizes, int n_in,
                              void* d_out, int out_size, void* d_ws, size_t ws_size,
                              hipStream_t stream) {
  (void)in_sizes; (void)n_in; (void)out_size; (void)ws_size;
  const float* x     = (const float*)d_in[0];
  const float* Wq    = (const float*)d_in[1];
  const float* Wdown = (const float*)d_in[2];
  const float* ln_g  = (const float*)d_in[3];
  const float* ln_b  = (const float*)d_in[4];
  const float* Wup   = (const float*)d_in[5];
  const float* Wo    = (const float*)d_in[6];
  const float* bo    = (const float*)d_in[7];
  float* out = (float*)d_out;

  char* w = (char*)d_ws;
  short* x_bf   = (short*)w;  w += (size_t)BT_ * C_    * 2;
  short* W1T    = (short*)w;  w += (size_t)832 * C_    * 2;
  short* WupT   = (short*)w;  w += (size_t)2*HD_ * R_  * 2;
  short* WoT    = (short*)w;  w += (size_t)HD_ * C_    * 2;
  short* ckv    = (short*)w;  w += (size_t)BT_ * R_    * 2;
  short* qb     = (short*)w;  w += (size_t)BT_ * HD_   * 2;
  short* kb     = (short*)w;  w += (size_t)BT_ * HD_   * 2;
  short* vt     = (short*)w;  w += (size_t)BT_ * HD_   * 2;
  short* att    = (short*)w;  w += (size_t)BT_ * HD_   * 2;
  float* cs_t   = (float*)w;  w += (size_t)T_ * 32 * 4;
  float* sn_t   = (float*)w;  w += (size_t)T_ * 32 * 4;

  prep_conv<<<NCONV + 1360, 256, 0, stream>>>(x, x_bf, Wq, Wdown, Wup, Wo,
                                              W1T, WupT, WoT, cs_t, sn_t);

  // q (*SC2, +rope) and LN(ckv) in ONE pass over x:  x @ [Wq | Wdown]
  gemm64<0><<<dim3(BT_/128, 13), 256, 0, stream>>>(
      x_bf, W1T, BT_, 832, C_, nullptr, ln_g, ln_b, qb, ckv, cs_t, sn_t);

  // kv = ckv @ Wup: k (+rope) natural layout, v transposed via LDS
  gemm64<1><<<dim3(BT_/128, 24), 256, 0, stream>>>(
      ckv, WupT, BT_, 2*HD_, R_, nullptr, nullptr, nullptr, kb, vt, cs_t, sn_t);

  attn_mfma<<<dim3(B_*H_, 16), 256, 0, stream>>>(qb, kb, vt, att);

  // out = att @ Wo + bo
  gemm64<2><<<dim3(BT_/128, 12), 256, 0, stream>>>(
      att, WoT, BT_, C_, HD_, out, bo, nullptr, nullptr, nullptr, nullptr, nullptr);
}

// Round 2
// 190.586 us; speedup vs baseline: 1.0859x; 1.0369x over previous
//
#include <hip/hip_runtime.h>
#include <hip/hip_bf16.h>
#include <math.h>

#define B_ 4
#define T_ 2048
#define C_ 768
#define H_ 12
#define D_ 64
#define R_ 64
#define BT_ (B_*T_)   /* 8192 */
#define HD_ (H_*D_)   /* 768  */

typedef __attribute__((ext_vector_type(8))) short bf16x8;
typedef __attribute__((ext_vector_type(4))) float f32x4;
typedef __attribute__((ext_vector_type(16))) float f32x16;

__device__ inline short f2bf(float f) {
  union { float f; unsigned u; } x; x.f = f;
  unsigned r = x.u + 0x7fffu + ((x.u >> 16) & 1u);
  return (short)(r >> 16);
}
__device__ inline unsigned pk_bf16(float a, float b) {
#if __has_builtin(__builtin_amdgcn_cvt_pk_bf16_f32)
  auto t = __builtin_amdgcn_cvt_pk_bf16_f32(a, b);
  unsigned u; __builtin_memcpy(&u, &t, sizeof(unsigned)); return u;
#else
  union { float f; unsigned u; } x, y; x.f = a; y.f = b;
  unsigned ra = (x.u + 0x7fffu + ((x.u >> 16) & 1u)) >> 16;
  unsigned rb = (y.u + 0x7fffu + ((y.u >> 16) & 1u)) & 0xffff0000u;
  return ra | rb;
#endif
}
__device__ inline float fexp2(float x) {
#if __has_builtin(__builtin_amdgcn_exp2f)
  return __builtin_amdgcn_exp2f(x);
#else
  return exp2f(x);
#endif
}
// cross-half (lane i <-> lane i+32) word swap:
// a <- {a.lanes0-31, b.lanes0-31}; b <- {a.lanes32-63, b.lanes32-63}
__device__ inline void pswap(unsigned &a, unsigned &b) {
#if __has_builtin(__builtin_amdgcn_permlane32_swap)
  auto r = __builtin_amdgcn_permlane32_swap((int)a, (int)b, false, false);
  unsigned u[2]; __builtin_memcpy(u, &r, 8);
  a = u[0]; b = u[1];
#else
  unsigned ax = __shfl_xor(a, 32), bx = __shfl_xor(b, 32);
  bool hi = (threadIdx.x & 32) != 0;
  unsigned na = hi ? bx : a;
  unsigned nb = hi ? b : ax;
  a = na; b = nb;
#endif
}
typedef __attribute__((address_space(3))) unsigned lds_u32;
typedef __attribute__((address_space(1))) const unsigned glb_u32;
__device__ inline void gload_lds16(const void* g, void* l) {
  __builtin_amdgcn_global_load_lds((glb_u32*)g, (lds_u32*)l, 16, 0, 0);
}

// ---------------- fused convert(x) + weight transposes + RoPE table ----------------
__device__ inline void ttile(const float* __restrict__ src, short* __restrict__ dst,
                             int K, int N, int k0, int n0, int tid, float (*tl)[33]) {
  int tx = tid & 31, ty = tid >> 5;
  #pragma unroll
  for (int r = 0; r < 4; ++r)
    tl[ty + 8 * r][tx] = src[(size_t)(k0 + ty + 8 * r) * N + n0 + tx];
  __syncthreads();
  #pragma unroll
  for (int r = 0; r < 4; ++r)
    dst[(size_t)(n0 + ty + 8 * r) * K + k0 + tx] = f2bf(tl[tx][ty + 8 * r]);
}

#define NCONV (BT_*C_/4/256)   /* 6144 blocks for x convert */

__global__ __launch_bounds__(256) void prep_conv(
    const float* __restrict__ x, short* __restrict__ x_bf,
    const float* __restrict__ Wq, const float* __restrict__ Wd,
    const float* __restrict__ Wup, const float* __restrict__ Wo,
    short* __restrict__ W1T, short* __restrict__ WupT, short* __restrict__ WoT,
    float* __restrict__ cs, float* __restrict__ sn) {
  __shared__ float tl[32][33];
  int tid = threadIdx.x;
  if (blockIdx.x < NCONV) {          // convert x -> bf16
    int i = blockIdx.x * 256 + tid;
    float4 v = ((const float4*)x)[i];
    short4 o;
    o.x = f2bf(v.x); o.y = f2bf(v.y); o.z = f2bf(v.z); o.w = f2bf(v.w);
    ((short4*)x_bf)[i] = o;
    return;
  }
  int blk = blockIdx.x - NCONV;
  if (blk < 576) {                    // Wq: K=768,N=768 -> W1T rows 0..767
    int tk = blk % 24, tn = blk / 24;
    ttile(Wq, W1T, 768, 768, tk * 32, tn * 32, tid, tl);
  } else if (blk < 624) {             // Wd: K=768,N=64 -> W1T rows 768..831
    int l = blk - 576; int tk = l % 24, tn = l / 24;
    ttile(Wd, W1T + (size_t)768 * 768, 768, 64, tk * 32, tn * 32, tid, tl);
  } else if (blk < 720) {             // Wup: K=64,N=1536
    int l = blk - 624; int tk = l % 2, tn = l / 2;
    ttile(Wup, WupT, 64, 1536, tk * 32, tn * 32, tid, tl);
  } else if (blk < 1296) {            // Wo: K=768,N=768
    int l = blk - 720; int tk = l % 24, tn = l / 24;
    ttile(Wo, WoT, 768, 768, tk * 32, tn * 32, tid, tl);
  } else {                            // rope table
    int base = (blk - 1296) * 1024;
    #pragma unroll
    for (int i = 0; i < 4; ++i) {
      int idx = base + tid + i * 256;
      int j = idx & 31, t = idx >> 5;
      float invf = exp2f(-(float)j * (13.287712379549449f / 32.f)); // 10000^(-j/32)
      float a = (float)t * invf;
      cs[idx] = cosf(a);
      sn[idx] = sinf(a);
    }
  }
}

// ---------------- 128x64-tile GEMM ----------------
// C[M,N] = A[M,K](bf16) * Bt[N,K](bf16)^T, BK=64. Wave w owns rows [w*32,+32).
// MODE 0: y<12 -> q*SC2+rope -> ob0 [BH][T][64]; y==12 -> LN(ckv) -> ob1 [M][64]
// MODE 1: y<12 -> k+rope -> ob0; y>=12 -> v transposed -> ob1 [BH*64][T]
// MODE 2: out0[row*N+col] = acc + bias[col]
#define SC2_ 0.18033688f   /* 0.125 * log2(e) */

template<int MODE>
__global__ __launch_bounds__(256) void gemm64(
    const short* __restrict__ A, const short* __restrict__ Bt,
    int M, int N, int K,
    float* __restrict__ out0, const float* __restrict__ bias,
    const float* __restrict__ bias2,
    short* __restrict__ ob0, short* __restrict__ ob1,
    const float* __restrict__ cs, const float* __restrict__ sn)
{
  __shared__ short SM[128 * 64 + 64 * 64];  // As (16KB) | Bs (8KB)
  short* As = SM;
  short* Bs = SM + 128 * 64;
  const int m0 = blockIdx.x * 128;
  const int n0 = blockIdx.y * 64;
  const int tid = threadIdx.x, lane = tid & 63, w = tid >> 6;
  const int fr = lane & 15, fk = (lane >> 4) * 8;
  const int rstage = lane >> 3;
  const int cstage = (lane & 7) * 8;

  f32x4 acc[2][4] = {};

  for (int k0 = 0; k0 < K; k0 += 64) {
    __syncthreads();
    #pragma unroll
    for (int i = 0; i < 4; ++i) {          // A: 16 chunks
      int c = w * 4 + i;
      int r = c * 8 + rstage;
      gload_lds16(&A[(size_t)(m0 + r) * K + k0 + cstage], &As[c * 512]);
    }
    #pragma unroll
    for (int i = 0; i < 2; ++i) {          // B: 8 chunks
      int c = w * 2 + i;
      int r = c * 8 + rstage;
      gload_lds16(&Bt[(size_t)(n0 + r) * K + k0 + cstage], &Bs[c * 512]);
    }
    __syncthreads();
    #pragma unroll
    for (int kk = 0; kk < 64; kk += 32) {
      bf16x8 a[2], b[4];
      a[0] = *(const bf16x8*)&As[(w * 32 +      fr) * 64 + kk + fk];
      a[1] = *(const bf16x8*)&As[(w * 32 + 16 + fr) * 64 + kk + fk];
      #pragma unroll
      for (int ni = 0; ni < 4; ++ni)
        b[ni] = *(const bf16x8*)&Bs[(ni * 16 + fr) * 64 + kk + fk];
      #pragma unroll
      for (int mi = 0; mi < 2; ++mi)
        #pragma unroll
        for (int ni = 0; ni < 4; ++ni)
          acc[mi][ni] = __builtin_amdgcn_mfma_f32_16x16x32_bf16(a[mi], b[ni], acc[mi][ni], 0, 0, 0);
    }
  }

  const int er = (lane >> 4) * 4, ec = lane & 15;

  if constexpr (MODE == 2) {
    #pragma unroll
    for (int mi = 0; mi < 2; ++mi)
      #pragma unroll
      for (int r = 0; r < 4; ++r) {
        int row = m0 + w * 32 + mi * 16 + er + r;
        #pragma unroll
        for (int ni = 0; ni < 4; ++ni) {
          int col = n0 + ni * 16 + ec;
          out0[(size_t)row * N + col] = acc[mi][ni][r] + bias[col];
        }
      }
    return;
  }

  if (n0 < 768) {  // q (MODE0) or k (MODE1), fused RoPE (+ SC2 scale for q)
    int h = n0 >> 6;
    #pragma unroll
    for (int mi = 0; mi < 2; ++mi)
      #pragma unroll
      for (int r = 0; r < 4; ++r) {
        int row = m0 + w * 32 + mi * 16 + er + r;
        int t = row & (T_ - 1), bb = row >> 11;
        short* dst = ob0 + (((size_t)(bb * H_ + h)) * T_ + t) * 64;
        #pragma unroll
        for (int ni = 0; ni < 2; ++ni) {
          int d = ni * 16 + ec;
          float c = cs[t * 32 + d], s = sn[t * 32 + d];
          if constexpr (MODE == 0) { c *= SC2_; s *= SC2_; }
          float x0 = acc[mi][ni][r], x1 = acc[mi][ni + 2][r];
          dst[d]      = f2bf(x0 * c - x1 * s);
          dst[d + 32] = f2bf(x1 * c + x0 * s);
        }
      }
  } else if constexpr (MODE == 0) {
    // ckv tile (n0 == 768): fused LayerNorm. bias=ln_g, bias2=ln_b
    #pragma unroll
    for (int mi = 0; mi < 2; ++mi)
      #pragma unroll
      for (int r = 0; r < 4; ++r) {
        float s = 0.f, s2 = 0.f;
        #pragma unroll
        for (int ni = 0; ni < 4; ++ni) { float v = acc[mi][ni][r]; s += v; s2 += v*v; }
        #pragma unroll
        for (int off = 1; off < 16; off <<= 1) {
          s  += __shfl_xor(s, off);
          s2 += __shfl_xor(s2, off);
        }
        float mu = s * (1.f/64.f);
        float var = s2 * (1.f/64.f) - mu * mu;
        float rstd = rsqrtf(var + 1e-5f);
        int row = m0 + w * 32 + mi * 16 + er + r;
        #pragma unroll
        for (int ni = 0; ni < 4; ++ni) {
          int d = ni * 16 + ec;
          ob1[(size_t)row * 64 + d] = f2bf((acc[mi][ni][r] - mu) * rstd * bias[d] + bias2[d]);
        }
      }
  } else {
    // MODE 1 v tile: acc -> wave-private LDS (stride 40) -> coalesced vt stores
    __syncthreads();   // all waves done reading As/Bs
    short* Wl = SM + w * 2560;     // 64 d-rows x 40 shorts
    int h = (n0 - 768) >> 6;
    #pragma unroll
    for (int mi = 0; mi < 2; ++mi) {
      int tl0 = mi * 16 + er;
      #pragma unroll
      for (int ni = 0; ni < 4; ++ni) {
        int d = ni * 16 + ec;
        uint2 uu;
        uu.x = pk_bf16(acc[mi][ni][0], acc[mi][ni][1]);
        uu.y = pk_bf16(acc[mi][ni][2], acc[mi][ni][3]);
        *(uint2*)&Wl[d * 40 + tl0] = uu;
      }
    }
    int bb = m0 >> 11;
    int tg0 = (m0 & (T_ - 1)) + w * 32;
    int dl = lane >> 2, tl = (lane & 3) * 8;
    #pragma unroll
    for (int j = 0; j < 4; ++j) {
      int d = j * 16 + dl;
      uint4 vv = *(const uint4*)&Wl[d * 40 + tl];
      *(uint4*)&ob1[((size_t)(bb * H_ + h) * 64 + d) * T_ + tg0 + tl] = vv;
    }
  }
}

// ---------------- MFMA flash attention v9 ----------------
// v8 + SIMD load-balance fix. v8 put the long-range q-tile (qt1=31-y) on waves
// 0-1 and the short one (qt2=y) on waves 2-3 in EVERY block -> SIMDs 0/1
// carried 24.5 avg compute tiles vs 8.5 on SIMDs 2/3 (3:1 skew; MfmaUtil stuck
// at 15% = measured skew). v9: block u owns q-tiles {4u..4u+3} with ranges
// {2u+1,2u+1,2u+2,2u+2} -> <=1-tile intra-block skew, all 4 SIMDs equal.
// Variable block duration handled by LPT: u = 15-blockIdx.y so longest blocks
// dispatch first (3x CU oversubscription). Also: -30% staged tiles (13056 vs
// 18816 block-tiles), no dead-tile churn (max 1 inactive tile per wave), and
// the per-tile __shfl_xor(ls,32) (DS-pipe op) is deferred to one epilogue
// shuffle; l-sum tree-reduced.
// 32x32 C/D layout (m74/m101): col=lane&31, row=(reg&3)+8*(reg>>2)+4*(lane>>5).
__global__ __launch_bounds__(256) void attn_mfma(
    const short* __restrict__ qgl, const short* __restrict__ kg,
    const short* __restrict__ vtg, short* __restrict__ o)
{
  // [buf][0=K,1=V][8 chunks * 512 shorts]; chunk c=kh*4+ks:
  //   K: K[kt+kh*32+(L&31)][ks*16+(L>>5)*8]   V: V^T[dt*32+(L&31)][kt+ks*16+(L>>5)*8]
  __shared__ short SMa[2][2][8 * 512];   // 32 KB total

  const int bh = blockIdx.x;           // 0..47 (48 = 0 mod 8: same-bh blocks share an XCD)
  const int u  = 15 - blockIdx.y;      // LPT: longest block (u=15, 32 tiles) first
  const int tid = threadIdx.x, lane = tid & 63, w = tid >> 6;
  const int q32 = lane & 31, half = lane >> 5;
  const short* kb  = kg  + (size_t)bh * T_ * 64;
  const short* vtb = vtg + (size_t)bh * 64 * T_;
  const int b = bh / H_, h = bh - b * H_;

  const int wq = 4 * u + w;            // this wave's 32-row q-tile (0..63)
  const int q0 = wq * 32;
  const int last_w = (wq >> 1) * 64;   // diagonal k-tile start for this wave
  const int qidx = q0 + q32;
  const int kend = (2 * u + 1) * 64;   // block stages k-tiles 0..2u+1

  // Q B-frags: bq[ks] = Q[q0+q32][ks*16 + half*8 .. +8]
  const short* qrow = qgl + ((size_t)bh * T_ + qidx) * 64;
  bf16x8 bq[4];
  #pragma unroll
  for (int ks = 0; ks < 4; ++ks)
    bq[ks] = *(const bf16x8*)&qrow[ks * 16 + half * 8];

  f32x16 oacc[2] = {};
  float lrun = 0.f;

  auto stage = [&](int buf, int kt) {
    #pragma unroll
    for (int i = 0; i < 2; ++i) {      // wave w stages chunks {2w, 2w+1}
      int c = w * 2 + i;
      int kh = c >> 2, ks = c & 3;
      gload_lds16(kb + (size_t)(kt + kh * 32 + q32) * 64 + ks * 16 + half * 8,
                  &SMa[buf][0][c * 512]);
      gload_lds16(vtb + (size_t)(kh * 32 + q32) * T_ + kt + ks * 16 + half * 8,
                  &SMa[buf][1][c * 512]);
    }
  };

  stage(0, 0);
  __syncthreads();                     // buf0 ready

  int cur = 0;
  for (int kt = 0; kt <= kend; kt += 64) {
    if (kt + 64 <= kend) stage(cur ^ 1, kt + 64);   // async prefetch next tile

    if (kt <= last_w) {
      const short* Kc = &SMa[cur][0][0];
      const short* Vc = &SMa[cur][1][0];
      const bool diag = (kt == last_w);
      const int dkh = diag ? (wq & 1) : 2;  // which kh is diagonal-masked
      const bool skip1 = diag && ((wq & 1) == 0);

      bf16x8 bp[4];
      #pragma unroll
      for (int kh = 0; kh < 2; ++kh) {
        if (kh == 1 && skip1) break;    // fully-masked upper half of diag tile
        f32x16 sacc = {};
        __builtin_amdgcn_s_setprio(1);
        #pragma unroll
        for (int ks = 0; ks < 4; ++ks) {
          bf16x8 a = *(const bf16x8*)&Kc[(kh * 4 + ks) * 512 + lane * 8];
          sacc = __builtin_amdgcn_mfma_f32_32x32x16_bf16(a, bq[ks], sacc, 0, 0, 0);
        }
        __builtin_amdgcn_s_setprio(0);
        float pv[16];
        if (kh != dkh) {
          #pragma unroll
          for (int r = 0; r < 16; ++r) pv[r] = fexp2(sacc[r]);
        } else {
          #pragma unroll
          for (int r = 0; r < 16; ++r) {
            int key = kt + kh * 32 + (r & 3) + 8 * (r >> 2) + 4 * half;
            pv[r] = (key <= qidx) ? fexp2(sacc[r]) : 0.f;
          }
        }
        // tree-reduce l (short dep chains), defer cross-half shuffle to epilogue
        float t0 = (pv[0] + pv[1]) + (pv[2] + pv[3]);
        float t1 = (pv[4] + pv[5]) + (pv[6] + pv[7]);
        float t2 = (pv[8] + pv[9]) + (pv[10] + pv[11]);
        float t3 = (pv[12] + pv[13]) + (pv[14] + pv[15]);
        lrun += (t0 + t1) + (t2 + t3);
        // C-layout -> B-frag, in-register (no LDS):
        unsigned l0 = pk_bf16(pv[0],  pv[1]),  h0 = pk_bf16(pv[2],  pv[3]);
        unsigned l1 = pk_bf16(pv[4],  pv[5]),  h1 = pk_bf16(pv[6],  pv[7]);
        unsigned l2 = pk_bf16(pv[8],  pv[9]),  h2 = pk_bf16(pv[10], pv[11]);
        unsigned l3 = pk_bf16(pv[12], pv[13]), h3 = pk_bf16(pv[14], pv[15]);
        pswap(l0, l1); pswap(h0, h1);
        pswap(l2, l3); pswap(h2, h3);
        union { unsigned u[4]; bf16x8 v; } f0, f1;
        f0.u[0] = l0; f0.u[1] = h0; f0.u[2] = l1; f0.u[3] = h1;
        f1.u[0] = l2; f1.u[1] = h2; f1.u[2] = l3; f1.u[3] = h3;
        bp[2 * kh + 0] = f0.v;
        bp[2 * kh + 1] = f1.v;
      }

      __builtin_amdgcn_s_setprio(1);
      #pragma unroll
      for (int ks = 0; ks < 2; ++ks)
        #pragma unroll
        for (int dt = 0; dt < 2; ++dt) {
          bf16x8 av = *(const bf16x8*)&Vc[(dt * 4 + ks) * 512 + lane * 8];
          oacc[dt] = __builtin_amdgcn_mfma_f32_32x32x16_bf16(av, bp[ks], oacc[dt], 0, 0, 0);
        }
      if (!skip1) {
        #pragma unroll
        for (int ks = 2; ks < 4; ++ks)
          #pragma unroll
          for (int dt = 0; dt < 2; ++dt) {
            bf16x8 av = *(const bf16x8*)&Vc[(dt * 4 + ks) * 512 + lane * 8];
            oacc[dt] = __builtin_amdgcn_mfma_f32_32x32x16_bf16(av, bp[ks], oacc[dt], 0, 0, 0);
          }
      }
      __builtin_amdgcn_s_setprio(0);
    }

    __syncthreads();    // prefetch had a full compute phase to land before this drain
    cur ^= 1;
  }

  // epilogue: cross-half l reduce, scale, O^T (C-layout) -> wave-private LDS
  // (reusing dead K/V bufs) -> coalesced rows.
  float ltot = lrun + __shfl_xor(lrun, 32);
  float inv = 1.f / ltot;
  short* Pw = &SMa[0][0][0] + w * 2304;   // 32 rows x 72 shorts per wave
  #pragma unroll
  for (int dt = 0; dt < 2; ++dt)
    #pragma unroll
    for (int g2 = 0; g2 < 4; ++g2) {
      uint2 uu;
      uu.x = pk_bf16(oacc[dt][4 * g2 + 0] * inv, oacc[dt][4 * g2 + 1] * inv);
      uu.y = pk_bf16(oacc[dt][4 * g2 + 2] * inv, oacc[dt][4 * g2 + 3] * inv);
      *(uint2*)&Pw[q32 * 72 + dt * 32 + 8 * g2 + 4 * half] = uu;
    }
  int row = lane >> 1, seg = lane & 1;
  int t = q0 + row;
  short* orow = o + ((size_t)(b * T_ + t)) * HD_ + h * 64 + seg * 32;
  #pragma unroll
  for (int i = 0; i < 4; ++i) {
    uint4 vv = *(const uint4*)&Pw[row * 72 + seg * 32 + i * 8];
    *(uint4*)&orow[i * 8] = vv;
  }
}

// ---------------- launcher ----------------
extern "C" void kernel_launch(void* const* d_in, const int* in_sizes, int n_in,
                              void* d_out, int out_size, void* d_ws, size_t ws_size,
                              hipStream_t stream) {
  (void)in_sizes; (void)n_in; (void)out_size; (void)ws_size;
  const float* x     = (const float*)d_in[0];
  const float* Wq    = (const float*)d_in[1];
  const float* Wdown = (const float*)d_in[2];
  const float* ln_g  = (const float*)d_in[3];
  const float* ln_b  = (const float*)d_in[4];
  const float* Wup   = (const float*)d_in[5];
  const float* Wo    = (const float*)d_in[6];
  const float* bo    = (const float*)d_in[7];
  float* out = (float*)d_out;

  char* w = (char*)d_ws;
  short* x_bf   = (short*)w;  w += (size_t)BT_ * C_    * 2;
  short* W1T    = (short*)w;  w += (size_t)832 * C_    * 2;
  short* WupT   = (short*)w;  w += (size_t)2*HD_ * R_  * 2;
  short* WoT    = (short*)w;  w += (size_t)HD_ * C_    * 2;
  short* ckv    = (short*)w;  w += (size_t)BT_ * R_    * 2;
  short* qb     = (short*)w;  w += (size_t)BT_ * HD_   * 2;
  short* kb     = (short*)w;  w += (size_t)BT_ * HD_   * 2;
  short* vt     = (short*)w;  w += (size_t)BT_ * HD_   * 2;
  short* att    = (short*)w;  w += (size_t)BT_ * HD_   * 2;
  float* cs_t   = (float*)w;  w += (size_t)T_ * 32 * 4;
  float* sn_t   = (float*)w;  w += (size_t)T_ * 32 * 4;

  prep_conv<<<NCONV + 1360, 256, 0, stream>>>(x, x_bf, Wq, Wdown, Wup, Wo,
                                              W1T, WupT, WoT, cs_t, sn_t);

  // q (*SC2, +rope) and LN(ckv) in ONE pass over x:  x @ [Wq | Wdown]
  gemm64<0><<<dim3(BT_/128, 13), 256, 0, stream>>>(
      x_bf, W1T, BT_, 832, C_, nullptr, ln_g, ln_b, qb, ckv, cs_t, sn_t);

  // kv = ckv @ Wup: k (+rope) natural layout, v transposed via LDS
  gemm64<1><<<dim3(BT_/128, 24), 256, 0, stream>>>(
      ckv, WupT, BT_, 2*HD_, R_, nullptr, nullptr, nullptr, kb, vt, cs_t, sn_t);

  attn_mfma<<<dim3(B_*H_, 16), 256, 0, stream>>>(qb, kb, vt, att);

  // out = att @ Wo + bo
  gemm64<2><<<dim3(BT_/128, 12), 256, 0, stream>>>(
      att, WoT, BT_, C_, HD_, out, bo, nullptr, nullptr, nullptr, nullptr, nullptr);
}